// Round 5
// baseline (2630.154 us; speedup 1.0000x reference)
//
#include <hip/hip_runtime.h>

#define N_USERS 100000
#define N_ITEMS 50000
#define NTOT    150000        // N_USERS + N_ITEMS
#define E       128
#define NNZ     4800000
#define BATCH   4096
#define TILE    16            // rows per block (150000 = 16*9375, 8192 = 16*512)
#define CHUNK   4096
#define NCHUNK  37            // ceil(150000/4096)

typedef int v4i __attribute__((ext_vector_type(4)));

// ---- non-temporal load helpers (keep one-shot streams out of L3) ----
__device__ __forceinline__ int ldnt_i(const int* p) {
    return __builtin_nontemporal_load(p);
}
__device__ __forceinline__ float ldnt_f(const float* p) {
    return __builtin_nontemporal_load(p);
}
__device__ __forceinline__ long long ldnt_ll(const void* p) {
    return __builtin_nontemporal_load((const long long*)p);
}
__device__ __forceinline__ v4i ldnt_v4(const void* p) {
    return __builtin_nontemporal_load((const v4i*)p);
}

// ---------------------------------------------------------------------------
// CSR build 1: histogram of row indices (hist pre-zeroed by memset).
__global__ __launch_bounds__(256) void hist_kernel(const int* __restrict__ row,
                                                   int* __restrict__ hist) {
    int i = blockIdx.x * blockDim.x + threadIdx.x;
    const int stride = gridDim.x * blockDim.x;
    for (; i < NNZ; i += stride) atomicAdd(&hist[ldnt_i(row + i)], 1);
}

// CSR build 2a: per-chunk sums. grid = 2*NCHUNK (A then H), block 1024.
__global__ __launch_bounds__(1024) void scan_partial(const int* __restrict__ hA,
                                                     const int* __restrict__ hH,
                                                     int* __restrict__ psum) {
    const int adj = blockIdx.x / NCHUNK;
    const int chk = blockIdx.x % NCHUNK;
    const int* h = adj ? hH : hA;
    const int t = threadIdx.x;
    const int i0 = chk * CHUNK + t * 4;
    int s = 0;
    #pragma unroll
    for (int u = 0; u < 4; ++u) { const int i = i0 + u; if (i < NTOT) s += h[i]; }
    #pragma unroll
    for (int off = 32; off; off >>= 1) s += __shfl_down(s, off);
    __shared__ int ws[16];
    if ((t & 63) == 0) ws[t >> 6] = s;
    __syncthreads();
    if (t == 0) {
        int tot = 0;
        #pragma unroll
        for (int w = 0; w < 16; ++w) tot += ws[w];
        psum[blockIdx.x] = tot;
    }
}

// CSR build 2b: exclusive scan of the 2*NCHUNK partials (tiny, 1 thread).
__global__ __launch_bounds__(64) void scan_offsets(int* __restrict__ psum,
                                                   int* __restrict__ rA,
                                                   int* __restrict__ rH) {
    if (threadIdx.x == 0 && blockIdx.x == 0) {
        int run = 0;
        for (int j = 0; j < NCHUNK; ++j) { const int t = psum[j]; psum[j] = run; run += t; }
        rA[NTOT] = run;
        run = 0;
        for (int j = NCHUNK; j < 2 * NCHUNK; ++j) { const int t = psum[j]; psum[j] = run; run += t; }
        rH[NTOT] = run;
    }
}

// CSR build 2c: chunk-local exclusive scan + global offset; writes rowptr AND
// the scatter cursors (cursor buffer aliases the hist buffer — each element is
// read then overwritten by the same thread).
__global__ __launch_bounds__(1024) void scan_write(int* __restrict__ hA, int* __restrict__ hH,
                                                   const int* __restrict__ psum,
                                                   int* __restrict__ rA, int* __restrict__ rH) {
    const int adj = blockIdx.x / NCHUNK;
    const int chk = blockIdx.x % NCHUNK;
    int* h = adj ? hH : hA;          // hist in, cursor out (in place)
    int* r = adj ? rH : rA;
    const int t = threadIdx.x, lane = t & 63, wv = t >> 6;
    const int i0 = chk * CHUNK + t * 4;
    const int a0 = (i0 + 0 < NTOT) ? h[i0 + 0] : 0;
    const int a1 = (i0 + 1 < NTOT) ? h[i0 + 1] : 0;
    const int a2 = (i0 + 2 < NTOT) ? h[i0 + 2] : 0;
    const int a3 = (i0 + 3 < NTOT) ? h[i0 + 3] : 0;
    const int s = a0 + a1 + a2 + a3;
    int x = s;
    #pragma unroll
    for (int off = 1; off < 64; off <<= 1) {
        const int n = __shfl_up(x, off);
        if (lane >= off) x += n;
    }
    __shared__ int wsum[16], woff[16];
    if (lane == 63) wsum[wv] = x;
    __syncthreads();
    if (t == 0) {
        int acc = 0;
        #pragma unroll
        for (int w = 0; w < 16; ++w) { woff[w] = acc; acc += wsum[w]; }
    }
    __syncthreads();
    const int excl = psum[blockIdx.x] + woff[wv] + (x - s);
    if (i0 + 0 < NTOT) { r[i0 + 0] = excl;                h[i0 + 0] = excl; }
    if (i0 + 1 < NTOT) { r[i0 + 1] = excl + a0;           h[i0 + 1] = excl + a0; }
    if (i0 + 2 < NTOT) { r[i0 + 2] = excl + a0 + a1;      h[i0 + 2] = excl + a0 + a1; }
    if (i0 + 3 < NTOT) { r[i0 + 3] = excl + a0 + a1 + a2; h[i0 + 3] = excl + a0 + a1 + a2; }
}

// CSR build 3: scatter edges into CSR order as interleaved (col, val) int2.
__global__ __launch_bounds__(256) void scatter_kernel(const int* __restrict__ row,
                                                      const int* __restrict__ col,
                                                      const float* __restrict__ val,
                                                      int* __restrict__ cursor,
                                                      int2* __restrict__ ed) {
    int i = blockIdx.x * blockDim.x + threadIdx.x;
    const int stride = gridDim.x * blockDim.x;
    for (; i < NNZ; i += stride) {
        const int r = ldnt_i(row + i);
        const int c = ldnt_i(col + i);
        const float v = ldnt_f(val + i);
        const int p = atomicAdd(&cursor[r], 1);
        ed[p] = make_int2(c, __float_as_int(v));
    }
}

// generic int copy (rowptr relocation before the FINAL layer)
__global__ __launch_bounds__(256) void copy_int(const int* __restrict__ src,
                                                int* __restrict__ dst, int n) {
    const int i = blockIdx.x * blockDim.x + threadIdx.x;
    if (i < n) dst[i] = src[i];
}

// ---------------------------------------------------------------------------
// Row base as float4*, layer 0 reads straight from the input embeddings.
template<bool FIRST>
__device__ __forceinline__ const float4* rowbase(int c, const float* __restrict__ ue,
                                                 const float* __restrict__ ie,
                                                 const float* __restrict__ A) {
    if constexpr (FIRST)
        return (c < N_USERS) ? ((const float4*)ue + (size_t)c * (E / 4))
                             : ((const float4*)ie + (size_t)(c - N_USERS) * (E / 4));
    else
        return (const float4*)A + (size_t)c * (E / 4);
}

// One edge-pair FMA: q = (c0,v0,c1,v1); half 0 handles edge 0, half 1 edge 1.
template<bool FIRST>
__device__ __forceinline__ void pairfma(v4i q, const float* __restrict__ ue,
                                        const float* __restrict__ ie,
                                        const float* __restrict__ A,
                                        int sub, int half, float4& acc) {
    const int   c = half ? q[2] : q[0];
    const float v = __int_as_float(half ? q[3] : q[1]);
    const float4 xv = rowbase<FIRST>(c, ue, ie, A)[sub];
    acc.x = fmaf(v, xv.x, acc.x);
    acc.y = fmaf(v, xv.y, acc.y);
    acc.z = fmaf(v, xv.z, acc.z);
    acc.w = fmaf(v, xv.w, acc.w);
}

// Accumulate one CSR row: full wave, 2 edges per gather instruction
// (lanes 0-31 = even edge, lanes 32-63 = odd edge, each lane a 16B row slice).
// Returns this half-wave's partial (combine across halves happens in caller).
template<bool FIRST>
__device__ __forceinline__ float4 row_accum(const int* __restrict__ rp,
                                            const int2* __restrict__ ed,
                                            const float* __restrict__ ue,
                                            const float* __restrict__ ie,
                                            const float* __restrict__ A,
                                            int r, int sub, int half) {
    const int s = rp[r];
    const int e = rp[r + 1];
    float4 accA = {0.f, 0.f, 0.f, 0.f};
    float4 accB = {0.f, 0.f, 0.f, 0.f};
    int i = s;
    if (i < e && (i & 1)) {                 // leading edge to even-align pairs
        const long long t0 = ldnt_ll(ed + i);
        const int   c = (int)(t0 & 0xffffffffLL);
        const float v = half ? 0.f : __int_as_float((int)(t0 >> 32));
        const float4 xv = rowbase<FIRST>(c, ue, ie, A)[sub];
        accA.x = fmaf(v, xv.x, accA.x); accA.y = fmaf(v, xv.y, accA.y);
        accA.z = fmaf(v, xv.z, accA.z); accA.w = fmaf(v, xv.w, accA.w);
        ++i;
    }
    for (; i + 7 < e; i += 8) {             // 4 pairs = 8 edges, one 64B q-line
        const v4i q0 = ldnt_v4(ed + i);
        const v4i q1 = ldnt_v4(ed + i + 2);
        const v4i q2 = ldnt_v4(ed + i + 4);
        const v4i q3 = ldnt_v4(ed + i + 6);
        pairfma<FIRST>(q0, ue, ie, A, sub, half, accA);
        pairfma<FIRST>(q1, ue, ie, A, sub, half, accB);
        pairfma<FIRST>(q2, ue, ie, A, sub, half, accA);
        pairfma<FIRST>(q3, ue, ie, A, sub, half, accB);
    }
    for (; i + 1 < e; i += 2) {
        const v4i q = ldnt_v4(ed + i);
        pairfma<FIRST>(q, ue, ie, A, sub, half, accA);
    }
    if (i < e) {                            // trailing single edge
        const long long t0 = ldnt_ll(ed + i);
        const int   c = (int)(t0 & 0xffffffffLL);
        const float v = half ? 0.f : __int_as_float((int)(t0 >> 32));
        const float4 xv = rowbase<FIRST>(c, ue, ie, A)[sub];
        accA.x = fmaf(v, xv.x, accA.x); accA.y = fmaf(v, xv.y, accA.y);
        accA.z = fmaf(v, xv.z, accA.z); accA.w = fmaf(v, xv.w, accA.w);
    }
    return make_float4(accA.x + accB.x, accA.y + accB.y,
                       accA.z + accB.z, accA.w + accB.w);
}

// ---------------------------------------------------------------------------
// Fused layer: TILE rows of pos (adj) and dis (hp) into LDS, then
// ego_next = concat(pos,dis) @ W + b written straight out.
template<bool FIRST, bool FINAL>
__global__ __launch_bounds__(256) void fused_layer(
    const float* __restrict__ A,
    const float* __restrict__ ue, const float* __restrict__ ie,
    const int* __restrict__ rpA, const int2* __restrict__ edA,
    const int* __restrict__ rpH, const int2* __restrict__ edH,
    const float* __restrict__ Wk, const float* __restrict__ bk,
    const int* __restrict__ users, const int* __restrict__ items,
    float* __restrict__ out) {
    __shared__ float sP[TILE][E];
    __shared__ float sD[TILE][E];
    const int t    = threadIdx.x;
    const int lane = t & 63;
    const int sub  = lane & 31;              // 16B slice within the row
    const int half = lane >> 5;              // which edge of the pair
    const int wv   = t >> 6;                 // wave 0..3, 4 rows each
    const int r0   = blockIdx.x * TILE;

    // ---- phase 1: CSR register accumulation, rows -> LDS ----
    for (int rl = wv * 4; rl < wv * 4 + 4; ++rl) {
        const int slot = r0 + rl;
        int r = slot;
        if constexpr (FINAL)
            r = (slot < BATCH) ? users[slot] : (N_USERS + items[slot - BATCH]);
        const float4 ap = row_accum<FIRST>(rpA, edA, ue, ie, A, r, sub, half);
        const float4 ad = row_accum<FIRST>(rpH, edH, ue, ie, A, r, sub, half);
        // exchange: half0 finalizes pos, half1 finalizes dis (4 shuffles total)
        float4 send = half ? ap : ad;
        float4 recv;
        recv.x = __shfl_xor(send.x, 32);
        recv.y = __shfl_xor(send.y, 32);
        recv.z = __shfl_xor(send.z, 32);
        recv.w = __shfl_xor(send.w, 32);
        if (!half) {
            float4 fin = make_float4(ap.x + recv.x, ap.y + recv.y, ap.z + recv.z, ap.w + recv.w);
            ((float4*)&sP[rl][0])[sub] = fin;
        } else {
            float4 fin = make_float4(ad.x + recv.x, ad.y + recv.y, ad.z + recv.z, ad.w + recv.w);
            ((float4*)&sD[rl][0])[sub] = fin;
        }
    }
    __syncthreads();

    // ---- phase 2: [TILE,256] @ [256,128] + bias ----
    const int j = t & (E - 1);               // output column
    const int h = t >> 7;                    // row half: 0 or 1 (8 rows each)
    float acc[8];
    const float bj = bk[j];
    #pragma unroll
    for (int rr = 0; rr < 8; ++rr) acc[rr] = bj;

    #pragma unroll 4
    for (int i = 0; i < E; ++i) {
        const float w = Wk[(size_t)i * E + j];          // top half (pos)
        #pragma unroll
        for (int rr = 0; rr < 8; ++rr) acc[rr] = fmaf(sP[h * 8 + rr][i], w, acc[rr]);
    }
    #pragma unroll 4
    for (int i = 0; i < E; ++i) {
        const float w = Wk[(size_t)(E + i) * E + j];    // bottom half (dis)
        #pragma unroll
        for (int rr = 0; rr < 8; ++rr) acc[rr] = fmaf(sD[h * 8 + rr][i], w, acc[rr]);
    }

    #pragma unroll
    for (int rr = 0; rr < 8; ++rr)
        out[(size_t)(r0 + h * 8 + rr) * E + j] = acc[rr];
}

// ---------------------------------------------------------------------------
extern "C" void kernel_launch(void* const* d_in, const int* in_sizes, int n_in,
                              void* d_out, int out_size, void* d_ws, size_t ws_size,
                              hipStream_t stream) {
    const float* user_emb = (const float*)d_in[0];
    const float* item_emb = (const float*)d_in[1];
    const float* adj_val  = (const float*)d_in[2];
    const float* hp_val   = (const float*)d_in[3];
    const float* W        = (const float*)d_in[4];
    const float* bias     = (const float*)d_in[5];
    const int*   adj_row  = (const int*)d_in[6];
    const int*   adj_col  = (const int*)d_in[7];
    const int*   hp_row   = (const int*)d_in[8];
    const int*   hp_col   = (const int*)d_in[9];
    const int*   users    = (const int*)d_in[10];
    const int*   items    = (const int*)d_in[11];
    float* out = (float*)d_out;

    // ---- workspace layout: exactly 230,400,000 B (proven available) ----
    float* buf0 = (float*)d_ws;                       // ego ping      76.8 MB
    float* buf1 = buf0 + (size_t)NTOT * E;            // ego pong      76.8 MB
    int2*  edA  = (int2*)(buf1 + (size_t)NTOT * E);   // CSR edges A   38.4 MB
    int2*  edH  = edA + NNZ;                          // CSR edges H   38.4 MB

    // rowptrs + scan partials live in d_out (4 MB; fully overwritten by FINAL).
    int* rpA  = (int*)d_out;
    int* rpH  = rpA + (NTOT + 1);
    int* psum = rpH + (NTOT + 1);                     // 2*NCHUNK ints
    // hist/cursor aliases buf1 (dead until layer 0 writes it).
    int* curA = (int*)buf1;
    int* curH = curA + NTOT;
    // rowptr copies for the FINAL layer live in buf1 (dead during layer 2).
    int* rpA2 = (int*)buf1;
    int* rpH2 = rpA2 + (NTOT + 1);

    // ---- build CSR (once; reused across all 3 layers) ----
    hipMemsetAsync(curA, 0, (size_t)2 * NTOT * sizeof(int), stream);
    hist_kernel<<<2048, 256, 0, stream>>>(adj_row, curA);
    hist_kernel<<<2048, 256, 0, stream>>>(hp_row,  curH);
    scan_partial<<<2 * NCHUNK, 1024, 0, stream>>>(curA, curH, psum);
    scan_offsets<<<1, 64, 0, stream>>>(psum, rpA, rpH);
    scan_write<<<2 * NCHUNK, 1024, 0, stream>>>(curA, curH, psum, rpA, rpH);
    scatter_kernel<<<2048, 256, 0, stream>>>(adj_row, adj_col, adj_val, curA, edA);
    scatter_kernel<<<2048, 256, 0, stream>>>(hp_row,  hp_col,  hp_val,  curH, edH);

    // ---- 3 fused layers ----
    const int gridF = NTOT / TILE;            // 9375
    const int gridL = (2 * BATCH) / TILE;     // 512
    // k=0: (ue,ie) -> buf1
    fused_layer<true, false><<<gridF, 256, 0, stream>>>(
        nullptr, user_emb, item_emb, rpA, edA, rpH, edH,
        W, bias, nullptr, nullptr, buf1);
    // k=1: buf1 -> buf0
    fused_layer<false, false><<<gridF, 256, 0, stream>>>(
        buf1, nullptr, nullptr, rpA, edA, rpH, edH,
        W + (size_t)2 * E * E, bias + E, nullptr, nullptr, buf0);
    // move rowptrs out of d_out before the FINAL layer overwrites it
    copy_int<<<(2 * (NTOT + 1) + 255) / 256, 256, 0, stream>>>(rpA, rpA2, 2 * (NTOT + 1));
    // k=2: buf0 -> d_out (only the 8192 requested rows)
    fused_layer<false, true><<<gridL, 256, 0, stream>>>(
        buf0, nullptr, nullptr, rpA2, edA, rpH2, edH,
        W + (size_t)4 * E * E, bias + 2 * E, users, items, out);
}

// Round 6
// 1814.936 us; speedup vs baseline: 1.4492x; 1.4492x over previous
//
#include <hip/hip_runtime.h>

#define N_USERS 100000
#define N_ITEMS 50000
#define NTOT    150000        // N_USERS + N_ITEMS
#define E       128
#define NNZ     4800000
#define BATCH   4096
#define TILE    16            // rows per fused block (150000 = 16*9375, 8192 = 16*512)
#define BSH     10            // log2(rows per bucket)
#define BROWS   1024          // rows per bucket
#define NBK     147           // ceil(NTOT / BROWS)
#define SLOT    16            // write-combine entries per bucket

typedef int v4i __attribute__((ext_vector_type(4)));

// ---- load helpers ----
__device__ __forceinline__ int   ldnt_i(const int* p)   { return __builtin_nontemporal_load(p); }
__device__ __forceinline__ float ldnt_f(const float* p) { return __builtin_nontemporal_load(p); }
__device__ __forceinline__ v4i   ld_v4(const void* p)   { return *(const v4i*)p; }

// ---------------------------------------------------------------------------
// Build 1: per-bucket edge counts via LDS histograms (294 counters, no global
// contention beyond one flush per block).
__global__ __launch_bounds__(1024) void bucket_count(const int* __restrict__ rowA,
                                                     const int* __restrict__ rowH,
                                                     int* __restrict__ cntA,
                                                     int* __restrict__ cntH) {
    __shared__ int c[2 * NBK];
    for (int i = threadIdx.x; i < 2 * NBK; i += 1024) c[i] = 0;
    __syncthreads();
    int i = blockIdx.x * 1024 + threadIdx.x;
    const int stride = gridDim.x * 1024;
    for (; i < NNZ; i += stride) {
        atomicAdd(&c[ldnt_i(rowA + i) >> BSH], 1);
        atomicAdd(&c[NBK + (ldnt_i(rowH + i) >> BSH)], 1);
    }
    __syncthreads();
    for (int j = threadIdx.x; j < 2 * NBK; j += 1024) {
        const int v = c[j];
        if (v) atomicAdd(j < NBK ? (cntA + j) : (cntH + (j - NBK)), v);
    }
}

// Build 2: tiny serial scans -> bucket bases + scatter cursors.
__global__ __launch_bounds__(64) void bucket_scan(const int* __restrict__ cntA,
                                                  const int* __restrict__ cntH,
                                                  int* __restrict__ baseA, int* __restrict__ baseH,
                                                  int* __restrict__ gcurA, int* __restrict__ gcurH) {
    const int t = threadIdx.x;
    if (t == 0) {
        int run = 0;
        for (int j = 0; j < NBK; ++j) { baseA[j] = run; gcurA[j] = run; run += cntA[j]; }
        baseA[NBK] = run;
    } else if (t == 1) {
        int run = 0;
        for (int j = 0; j < NBK; ++j) { baseH[j] = run; gcurH[j] = run; run += cntH[j]; }
        baseH[NBK] = run;
    }
}

// Build 3: write-combining bucket scatter. Edges packed to int2
// {rowlocal<<18|col, valbits}; staged in LDS 16-entry slots per bucket,
// flushed as sequential chunks. Overflow entries go direct-to-global.
__global__ __launch_bounds__(1024) void wc_scatter(const int* __restrict__ rowA, const int* __restrict__ colA,
                                                   const float* __restrict__ valA,
                                                   const int* __restrict__ rowH, const int* __restrict__ colH,
                                                   const float* __restrict__ valH,
                                                   int* __restrict__ gcurA, int* __restrict__ gcurH,
                                                   int2* __restrict__ stA, int2* __restrict__ stH) {
    __shared__ int  lcnt[2 * NBK];
    __shared__ int2 lent[2 * NBK * SLOT];
    for (int i = threadIdx.x; i < 2 * NBK; i += 1024) lcnt[i] = 0;
    __syncthreads();
    const int stride = gridDim.x * 1024;
    const int rounds = (NNZ + stride - 1) / stride;
    for (int rd = 0; rd < rounds; ++rd) {
        const int i = rd * stride + blockIdx.x * 1024 + threadIdx.x;
        if (i < NNZ) {
            {   // A edge
                const int r = ldnt_i(rowA + i), cc = ldnt_i(colA + i);
                const float v = ldnt_f(valA + i);
                const int b = r >> BSH;
                const int2 pk = make_int2(((r & (BROWS - 1)) << 18) | cc, __float_as_int(v));
                const int n = atomicAdd(&lcnt[b], 1);
                if (n < SLOT) lent[b * SLOT + n] = pk;
                else          stA[atomicAdd(&gcurA[b], 1)] = pk;
            }
            {   // H edge
                const int r = ldnt_i(rowH + i), cc = ldnt_i(colH + i);
                const float v = ldnt_f(valH + i);
                const int b = r >> BSH;
                const int gb = NBK + b;
                const int2 pk = make_int2(((r & (BROWS - 1)) << 18) | cc, __float_as_int(v));
                const int n = atomicAdd(&lcnt[gb], 1);
                if (n < SLOT) lent[gb * SLOT + n] = pk;
                else          stH[atomicAdd(&gcurH[b], 1)] = pk;
            }
        }
        __syncthreads();
        const int thresh = (rd == rounds - 1) ? 1 : 8;
        for (int gb = threadIdx.x; gb < 2 * NBK; gb += 1024) {
            int n = lcnt[gb]; if (n > SLOT) n = SLOT;
            if (n >= thresh) {
                int*  gc = (gb < NBK) ? &gcurA[gb] : &gcurH[gb - NBK];
                int2* st = (gb < NBK) ? stA : stH;
                const int p = atomicAdd(gc, n);
                for (int j = 0; j < n; ++j) st[p + j] = lent[gb * SLOT + j];
                lcnt[gb] = 0;
            }
        }
        __syncthreads();
    }
}

// Build 4: per-bucket exact CSR + rowptr, all within an L2-resident window.
__global__ __launch_bounds__(1024) void bucket_csr(const int2* __restrict__ stA, const int2* __restrict__ stH,
                                                   const int* __restrict__ baseA, const int* __restrict__ baseH,
                                                   int* __restrict__ rpA, int* __restrict__ rpH,
                                                   int2* __restrict__ edA, int2* __restrict__ edH) {
    const int isH = blockIdx.x >= NBK;
    const int b   = isH ? blockIdx.x - NBK : blockIdx.x;
    const int2* st   = isH ? stH   : stA;
    const int*  base = isH ? baseH : baseA;
    int*  rp = isH ? rpH : rpA;
    int2* ed = isH ? edH : edA;
    const int s = base[b], e = base[b + 1];
    const int t = threadIdx.x, lane = t & 63, wv = t >> 6;
    __shared__ int cnt[BROWS];
    __shared__ int wsum[16], woff[16];
    cnt[t] = 0;
    __syncthreads();
    for (int i = s + t; i < e; i += 1024) atomicAdd(&cnt[st[i].x >> 18], 1);
    __syncthreads();
    const int v = cnt[t];
    int x = v;
    #pragma unroll
    for (int off = 1; off < 64; off <<= 1) {
        const int n = __shfl_up(x, off);
        if (lane >= off) x += n;
    }
    if (lane == 63) wsum[wv] = x;
    __syncthreads();
    if (t == 0) { int acc = 0; for (int w = 0; w < 16; ++w) { woff[w] = acc; acc += wsum[w]; } }
    __syncthreads();
    const int excl = woff[wv] + (x - v);
    const int rglob = (b << BSH) + t;
    if (rglob < NTOT) rp[rglob] = s + excl;
    __syncthreads();
    cnt[t] = excl;
    __syncthreads();
    for (int i = s + t; i < e; i += 1024) {
        const int2 pk = st[i];
        const int rl = pk.x >> 18;
        const int p = s + atomicAdd(&cnt[rl], 1);
        ed[p] = make_int2(pk.x & 0x3FFFF, pk.y);
    }
    if (t == 0 && b == 0) rp[NTOT] = NNZ;
}

// generic int copy (rowptr relocation before the FINAL layer)
__global__ __launch_bounds__(256) void copy_int(const int* __restrict__ src,
                                                int* __restrict__ dst, int n) {
    const int i = blockIdx.x * blockDim.x + threadIdx.x;
    if (i < n) dst[i] = src[i];
}

// ---------------------------------------------------------------------------
// Row base as float4*, layer 0 reads straight from the input embeddings.
template<bool FIRST>
__device__ __forceinline__ const float4* rowbase(int c, const float* __restrict__ ue,
                                                 const float* __restrict__ ie,
                                                 const float* __restrict__ A) {
    if constexpr (FIRST)
        return (c < N_USERS) ? ((const float4*)ue + (size_t)c * (E / 4))
                             : ((const float4*)ie + (size_t)(c - N_USERS) * (E / 4));
    else
        return (const float4*)A + (size_t)c * (E / 4);
}

template<bool FIRST>
__device__ __forceinline__ void pairfma(v4i q, const float* __restrict__ ue,
                                        const float* __restrict__ ie,
                                        const float* __restrict__ A,
                                        int sub, int half, float4& acc) {
    const int   c = half ? q[2] : q[0];
    const float v = __int_as_float(half ? q[3] : q[1]);
    const float4 xv = rowbase<FIRST>(c, ue, ie, A)[sub];
    acc.x = fmaf(v, xv.x, acc.x);
    acc.y = fmaf(v, xv.y, acc.y);
    acc.z = fmaf(v, xv.z, acc.z);
    acc.w = fmaf(v, xv.w, acc.w);
}

// Accumulate one CSR row: 2 edges per gather instruction (half-waves), cached loads.
template<bool FIRST>
__device__ __forceinline__ float4 row_accum(const int* __restrict__ rp,
                                            const int2* __restrict__ ed,
                                            const float* __restrict__ ue,
                                            const float* __restrict__ ie,
                                            const float* __restrict__ A,
                                            int r, int sub, int half) {
    const int s = rp[r];
    const int e = rp[r + 1];
    float4 accA = {0.f, 0.f, 0.f, 0.f};
    float4 accB = {0.f, 0.f, 0.f, 0.f};
    int i = s;
    if (i < e && (i & 1)) {                 // leading edge to even-align pairs
        const int2 t0 = ed[i];
        const float v = half ? 0.f : __int_as_float(t0.y);
        const float4 xv = rowbase<FIRST>(t0.x, ue, ie, A)[sub];
        accA.x = fmaf(v, xv.x, accA.x); accA.y = fmaf(v, xv.y, accA.y);
        accA.z = fmaf(v, xv.z, accA.z); accA.w = fmaf(v, xv.w, accA.w);
        ++i;
    }
    for (; i + 7 < e; i += 8) {             // 4 pairs = 8 edges
        const v4i q0 = ld_v4(ed + i);
        const v4i q1 = ld_v4(ed + i + 2);
        const v4i q2 = ld_v4(ed + i + 4);
        const v4i q3 = ld_v4(ed + i + 6);
        pairfma<FIRST>(q0, ue, ie, A, sub, half, accA);
        pairfma<FIRST>(q1, ue, ie, A, sub, half, accB);
        pairfma<FIRST>(q2, ue, ie, A, sub, half, accA);
        pairfma<FIRST>(q3, ue, ie, A, sub, half, accB);
    }
    for (; i + 1 < e; i += 2) {
        const v4i q = ld_v4(ed + i);
        pairfma<FIRST>(q, ue, ie, A, sub, half, accA);
    }
    if (i < e) {                            // trailing single edge
        const int2 t0 = ed[i];
        const float v = half ? 0.f : __int_as_float(t0.y);
        const float4 xv = rowbase<FIRST>(t0.x, ue, ie, A)[sub];
        accA.x = fmaf(v, xv.x, accA.x); accA.y = fmaf(v, xv.y, accA.y);
        accA.z = fmaf(v, xv.z, accA.z); accA.w = fmaf(v, xv.w, accA.w);
    }
    return make_float4(accA.x + accB.x, accA.y + accB.y,
                       accA.z + accB.z, accA.w + accB.w);
}

// ---------------------------------------------------------------------------
// Fused layer. FIRST also selects nt-stores for the output (L3-pollution A/B:
// layer 0 stores nt, layer 1 stores cached -> compare their FETCH next round).
template<bool FIRST, bool FINAL>
__global__ __launch_bounds__(256) void fused_layer(
    const float* __restrict__ A,
    const float* __restrict__ ue, const float* __restrict__ ie,
    const int* __restrict__ rpA, const int2* __restrict__ edA,
    const int* __restrict__ rpH, const int2* __restrict__ edH,
    const float* __restrict__ Wk, const float* __restrict__ bk,
    const int* __restrict__ users, const int* __restrict__ items,
    float* __restrict__ out) {
    __shared__ float sP[TILE][E];
    __shared__ float sD[TILE][E];
    const int t    = threadIdx.x;
    const int lane = t & 63;
    const int sub  = lane & 31;              // 16B slice within the row
    const int half = lane >> 5;              // which edge of the pair
    const int wv   = t >> 6;                 // wave 0..3, 4 rows each
    const int r0   = blockIdx.x * TILE;

    for (int rl = wv * 4; rl < wv * 4 + 4; ++rl) {
        const int slot = r0 + rl;
        int r = slot;
        if constexpr (FINAL)
            r = (slot < BATCH) ? users[slot] : (N_USERS + items[slot - BATCH]);
        const float4 ap = row_accum<FIRST>(rpA, edA, ue, ie, A, r, sub, half);
        const float4 ad = row_accum<FIRST>(rpH, edH, ue, ie, A, r, sub, half);
        float4 send = half ? ap : ad;
        float4 recv;
        recv.x = __shfl_xor(send.x, 32);
        recv.y = __shfl_xor(send.y, 32);
        recv.z = __shfl_xor(send.z, 32);
        recv.w = __shfl_xor(send.w, 32);
        if (!half) {
            ((float4*)&sP[rl][0])[sub] = make_float4(ap.x + recv.x, ap.y + recv.y,
                                                     ap.z + recv.z, ap.w + recv.w);
        } else {
            ((float4*)&sD[rl][0])[sub] = make_float4(ad.x + recv.x, ad.y + recv.y,
                                                     ad.z + recv.z, ad.w + recv.w);
        }
    }
    __syncthreads();

    // ---- phase 2: [TILE,256] @ [256,128] + bias ----
    const int j = t & (E - 1);
    const int h = t >> 7;
    float acc[8];
    const float bj = bk[j];
    #pragma unroll
    for (int rr = 0; rr < 8; ++rr) acc[rr] = bj;

    #pragma unroll 4
    for (int i = 0; i < E; ++i) {
        const float w = Wk[(size_t)i * E + j];
        #pragma unroll
        for (int rr = 0; rr < 8; ++rr) acc[rr] = fmaf(sP[h * 8 + rr][i], w, acc[rr]);
    }
    #pragma unroll 4
    for (int i = 0; i < E; ++i) {
        const float w = Wk[(size_t)(E + i) * E + j];
        #pragma unroll
        for (int rr = 0; rr < 8; ++rr) acc[rr] = fmaf(sD[h * 8 + rr][i], w, acc[rr]);
    }

    #pragma unroll
    for (int rr = 0; rr < 8; ++rr) {
        float* p = &out[(size_t)(r0 + h * 8 + rr) * E + j];
        if constexpr (FIRST) __builtin_nontemporal_store(acc[rr], p);
        else                 *p = acc[rr];
    }
}

// ---------------------------------------------------------------------------
extern "C" void kernel_launch(void* const* d_in, const int* in_sizes, int n_in,
                              void* d_out, int out_size, void* d_ws, size_t ws_size,
                              hipStream_t stream) {
    const float* user_emb = (const float*)d_in[0];
    const float* item_emb = (const float*)d_in[1];
    const float* adj_val  = (const float*)d_in[2];
    const float* hp_val   = (const float*)d_in[3];
    const float* W        = (const float*)d_in[4];
    const float* bias     = (const float*)d_in[5];
    const int*   adj_row  = (const int*)d_in[6];
    const int*   adj_col  = (const int*)d_in[7];
    const int*   hp_row   = (const int*)d_in[8];
    const int*   hp_col   = (const int*)d_in[9];
    const int*   users    = (const int*)d_in[10];
    const int*   items    = (const int*)d_in[11];
    float* out = (float*)d_out;

    // ---- workspace layout: exactly 230,400,000 B (proven available) ----
    float* buf0 = (float*)d_ws;                       // ego ping / build staging
    float* buf1 = buf0 + (size_t)NTOT * E;            // ego pong
    int2*  edA  = (int2*)(buf1 + (size_t)NTOT * E);   // CSR edges A   38.4 MB
    int2*  edH  = edA + NNZ;                          // CSR edges H   38.4 MB
    int2*  stA  = (int2*)buf0;                        // staging aliases buf0
    int2*  stH  = stA + NNZ;

    // scratch ints in d_out (4 MB; fully overwritten by the FINAL layer)
    int* rpA   = (int*)d_out;
    int* rpH   = rpA + (NTOT + 1);
    int* cntA  = rpH + (NTOT + 1);
    int* cntH  = cntA + NBK;
    int* baseA = cntH + NBK;
    int* baseH = baseA + (NBK + 1);
    int* gcurA = baseH + (NBK + 1);
    int* gcurH = gcurA + NBK;
    // rowptr copies for the FINAL layer live in buf1 (dead during layer 2)
    int* rpA2 = (int*)buf1;
    int* rpH2 = rpA2 + (NTOT + 1);

    // ---- build CSR (bucketed; once, reused across all 3 layers) ----
    hipMemsetAsync(cntA, 0, (size_t)2 * NBK * sizeof(int), stream);
    bucket_count<<<256, 1024, 0, stream>>>(adj_row, hp_row, cntA, cntH);
    bucket_scan<<<1, 64, 0, stream>>>(cntA, cntH, baseA, baseH, gcurA, gcurH);
    wc_scatter<<<256, 1024, 0, stream>>>(adj_row, adj_col, adj_val,
                                         hp_row, hp_col, hp_val,
                                         gcurA, gcurH, stA, stH);
    bucket_csr<<<2 * NBK, 1024, 0, stream>>>(stA, stH, baseA, baseH, rpA, rpH, edA, edH);

    // ---- 3 fused layers ----
    const int gridF = NTOT / TILE;            // 9375
    const int gridL = (2 * BATCH) / TILE;     // 512
    // k=0: (ue,ie) -> buf1   [nt-stores]
    fused_layer<true, false><<<gridF, 256, 0, stream>>>(
        nullptr, user_emb, item_emb, rpA, edA, rpH, edH,
        W, bias, nullptr, nullptr, buf1);
    // k=1: buf1 -> buf0      [cached stores]
    fused_layer<false, false><<<gridF, 256, 0, stream>>>(
        buf1, nullptr, nullptr, rpA, edA, rpH, edH,
        W + (size_t)2 * E * E, bias + E, nullptr, nullptr, buf0);
    // move rowptrs out of d_out before the FINAL layer overwrites it
    copy_int<<<(2 * (NTOT + 1) + 255) / 256, 256, 0, stream>>>(rpA, rpA2, 2 * (NTOT + 1));
    // k=2: buf0 -> d_out (only the 8192 requested rows)
    fused_layer<false, true><<<gridL, 256, 0, stream>>>(
        buf0, nullptr, nullptr, rpA2, edA, rpH2, edH,
        W + (size_t)4 * E * E, bias + 2 * E, users, items, out);
}